// Round 6
// baseline (18.748 us; speedup 1.0000x reference)
//
#include <hip/hip_runtime.h>
#include <math.h>

#define BATCH 4
#define NPTS  32
#define IMH   512
#define IMW   512
#define HB    64
#define TPW   128   // tile width  (32 lanes x 4 px)
#define TPH   16    // tile height (thread owns 2 adjacent rows; wave w owns rows 4w..4w+3)

// Single fused kernel, zero barriers, zero LDS, 8 px/thread.
// Cull uses only traj-direct data (x, y, z) -> waves with no surviving strokes
// skip the whole PCR spline and take a pure streaming-copy early exit.
__global__ __launch_bounds__(256) void fused_paint_kernel(
    const float* __restrict__ images, const float* __restrict__ traj,
    const float* __restrict__ colors, const float* __restrict__ brush,
    float* __restrict__ out) {
  int b = blockIdx.z;
  int t = threadIdx.x;
  int lane = t & 63;
  int w = t >> 6;
  int tx = t & 31, ty = t >> 5;
  int c0 = blockIdx.x * TPW, r0 = blockIdx.y * TPH;
  int col = c0 + tx * 4;
  int row = r0 + ty * 2;              // this thread: rows row, row+1
  size_t plane = (size_t)IMH * IMW;
  size_t base = (size_t)b * 4 * plane + (size_t)row * IMW + col;

  // Streaming loads first — HBM latency hides under cull/spline.
  float4 a0 = *(const float4*)(images + base);
  float4 b0 = *(const float4*)(images + base + IMW);
  float4 a1 = *(const float4*)(images + base + plane);
  float4 b1 = *(const float4*)(images + base + plane + IMW);
  float4 a2 = *(const float4*)(images + base + 2 * plane);
  float4 b2 = *(const float4*)(images + base + 2 * plane + IMW);
  float4 a3 = *(const float4*)(images + base + 3 * plane);
  float4 b3 = *(const float4*)(images + base + 3 * plane + IMW);

  // ---- cull from traj-direct data (no spline needed) ----
  const float* tb = traj + b * 4 * NPTS;
  float tsv = 0.f, xv = 0.f, yv = 0.f, zv = 0.f;
  if (lane < NPTS) {
    tsv = tb[0 * NPTS + lane];
    xv  = tb[1 * NPTS + lane];
    yv  = tb[2 * NPTS + lane];
    zv  = tb[3 * NPTS + lane];
  }
  float scale = fminf(fmaxf(zv, 0.001f), 1.0f);
  float iscv  = 1.0f / scale;
  // Exact support radius: 33.42*scale (alpha>0 disc 32 + bilinear sqrt(2)).
  float R = scale * 33.6f + 0.5f;
  float sx0 = (float)c0, sx1 = (float)(c0 + TPW - 1);
  float sy0 = (float)(r0 + w * 4), sy1 = sy0 + 3.f;
  bool pred = (lane < NPTS) && (zv > 0.f) &&
              (xv + R >= sx0) && (xv - R <= sx1) &&
              (yv + R >= sy0) && (yv - R <= sy1);
  unsigned long long mask = __ballot(pred);

  if (mask == 0ull) {                 // pure streaming copy (wave-uniform)
    *(float4*)(out + base)                 = a0;
    *(float4*)(out + base + IMW)           = b0;
    *(float4*)(out + base + plane)         = a1;
    *(float4*)(out + base + plane + IMW)   = b1;
    *(float4*)(out + base + 2 * plane)     = a2;
    *(float4*)(out + base + 2 * plane + IMW) = b2;
    *(float4*)(out + base + 3 * plane)     = a3;
    *(float4*)(out + base + 3 * plane + IMW) = b3;
    return;
  }

  // ---- per-wave spline via PCR (lane k = node k), only when needed ----
  float ts1 = __shfl_down(tsv, 1);
  float x1  = __shfl_down(xv, 1);
  float y1  = __shfl_down(yv, 1);
  float hv  = ts1 - tsv;
  float sxv = (x1 - xv) / hv;
  float syv = (y1 - yv) / hv;
  float am  = __shfl_up(hv, 1);
  float smx = __shfl_up(sxv, 1);
  float smy = __shfl_up(syv, 1);
  bool interior = (lane >= 1) && (lane <= NPTS - 2);
  float A_ = interior ? am : 0.f;
  float C_ = interior ? hv : 0.f;
  float B_ = interior ? 2.0f * (am + hv) : 1.f;
  float Rx = interior ? 6.0f * (sxv - smx) : 0.f;
  float Ry = interior ? 6.0f * (syv - smy) : 0.f;

  #pragma unroll
  for (int d = 1; d < NPTS; d <<= 1) {
    int lo = lane - d; lo = lo < 0 ? 0 : lo;
    int hi = lane + d; hi = hi > NPTS - 1 ? NPTS - 1 : hi;
    float a_lo = __shfl(A_, lo), b_lo = __shfl(B_, lo), c_lo = __shfl(C_, lo);
    float rx_lo = __shfl(Rx, lo), ry_lo = __shfl(Ry, lo);
    float a_hi = __shfl(A_, hi), b_hi = __shfl(B_, hi), c_hi = __shfl(C_, hi);
    float rx_hi = __shfl(Rx, hi), ry_hi = __shfl(Ry, hi);
    float alpha = A_ / b_lo;
    float gamma = C_ / b_hi;
    B_ = B_ - alpha * c_lo - gamma * a_hi;
    Rx = Rx - alpha * rx_lo - gamma * rx_hi;
    Ry = Ry - alpha * ry_lo - gamma * ry_hi;
    A_ = -alpha * a_lo;
    C_ = -gamma * c_hi;
  }
  float Mxv = Rx / B_;   // M[0]=M[31]=0 via identity rows
  float Myv = Ry / B_;

  float Mx1  = __shfl_down(Mxv, 1);
  float My1  = __shfl_down(Myv, 1);
  float sx30 = __shfl(sxv, NPTS - 2);
  float sy30 = __shfl(syv, NPTS - 2);
  float h30  = __shfl(hv,  NPTS - 2);
  float Mx30 = __shfl(Mxv, NPTS - 2);
  float My30 = __shfl(Myv, NPTS - 2);
  float Mx31 = __shfl(Mxv, NPTS - 1);
  float My31 = __shfl(Myv, NPTS - 1);

  float dX, dY;
  if (lane < NPTS - 1) {
    dX = sxv - hv * (2.0f * Mxv + Mx1) / 6.0f;
    dY = syv - hv * (2.0f * Myv + My1) / 6.0f;
  } else {
    dX = sx30 + h30 * (2.0f * Mx31 + Mx30) / 6.0f;
    dY = sy30 + h30 * (2.0f * My31 + My30) / 6.0f;
  }
  float cthv = 1.f, sthv = 0.f;
  {
    float r2 = dX * dX + dY * dY;
    if (r2 > 0.f) { float inv = 1.0f / sqrtf(r2); cthv = dX * inv; sthv = -dY * inv; }
  }

  float cr = colors[b * 4 + 0], cg = colors[b * 4 + 1];
  float cb = colors[b * 4 + 2], ca = colors[b * 4 + 3];

  // g = 1 - img, per row r (index 0/1) per px i
  float gr[2][4], gg[2][4], gb[2][4];
  gr[0][0] = 1.f - a0.x; gr[0][1] = 1.f - a0.y; gr[0][2] = 1.f - a0.z; gr[0][3] = 1.f - a0.w;
  gr[1][0] = 1.f - b0.x; gr[1][1] = 1.f - b0.y; gr[1][2] = 1.f - b0.z; gr[1][3] = 1.f - b0.w;
  gg[0][0] = 1.f - a1.x; gg[0][1] = 1.f - a1.y; gg[0][2] = 1.f - a1.z; gg[0][3] = 1.f - a1.w;
  gg[1][0] = 1.f - b1.x; gg[1][1] = 1.f - b1.y; gg[1][2] = 1.f - b1.z; gg[1][3] = 1.f - b1.w;
  gb[0][0] = 1.f - a2.x; gb[0][1] = 1.f - a2.y; gb[0][2] = 1.f - a2.z; gb[0][3] = 1.f - a2.w;
  gb[1][0] = 1.f - b2.x; gb[1][1] = 1.f - b2.y; gb[1][2] = 1.f - b2.z; gb[1][3] = 1.f - b2.w;

  const float* bA = brush + 3 * HB * HB;   // alpha plane, 16KB -> L1-resident

  // Surviving strokes in ascending k (compositing order exact).
  while (mask) {
    int src = __builtin_ctzll(mask);
    mask &= mask - 1;
    float spx = __shfl(xv, src), spy = __shfl(yv, src);
    float cth = __shfl(cthv, src), sth = __shfl(sthv, src), isc = __shfl(iscv, src);
    float dx0 = (float)col - spx;
    float cdx = cth * isc, sdx = sth * isc;
    #pragma unroll
    for (int r = 0; r < 2; ++r) {
      float dy = (float)(row + r) - spy;
      float lxb = (cth * dx0 - sth * dy) * isc + 0.5f * (HB - 1);
      float lyb = (sth * dx0 + cth * dy) * isc + 0.5f * (HB - 1);
      #pragma unroll
      for (int i = 0; i < 4; ++i) {
        float lx = lxb + cdx * (float)i;
        float ly = lyb + sdx * (float)i;
        if (lx <= -1.f || lx >= (float)HB || ly <= -1.f || ly >= (float)HB) continue;
        float x0f = floorf(lx), y0f = floorf(ly);
        float wx = lx - x0f, wy = ly - y0f;
        int x0 = (int)x0f, y0 = (int)y0f;
        int x1i = x0 + 1, y1i = y0 + 1;
        bool xv0 = (x0  >= 0) && (x0  < HB);
        bool xv1 = (x1i >= 0) && (x1i < HB);
        bool yv0 = (y0  >= 0) && (y0  < HB);
        bool yv1 = (y1i >= 0) && (y1i < HB);
        int xc0 = min(max(x0,  0), HB - 1);
        int xc1 = min(max(x1i, 0), HB - 1);
        int yc0 = min(max(y0,  0), HB - 1);
        int yc1 = min(max(y1i, 0), HB - 1);
        float f00 = (xv0 && yv0) ? 1.f : 0.f;
        float f01 = (xv1 && yv0) ? 1.f : 0.f;
        float f10 = (xv0 && yv1) ? 1.f : 0.f;
        float f11 = (xv1 && yv1) ? 1.f : 0.f;
        float v00 = bA[yc0 * HB + xc0] * f00;
        float v01 = bA[yc0 * HB + xc1] * f01;
        float v10 = bA[yc1 * HB + xc0] * f10;
        float v11 = bA[yc1 * HB + xc1] * f11;
        float w00 = (1.f - wx) * (1.f - wy);
        float w01 = wx * (1.f - wy);
        float w10 = (1.f - wx) * wy;
        float w11 = wx * wy;
        float asamp = v00 * w00 + v01 * w01 + v10 * w10 + v11 * w11;
        float aa    = ca * asamp;                                      // sprite alpha
        float wsum  = f00 * w00 + f01 * w01 + f10 * w10 + f11 * w11;   // rgb coverage
        float om = 1.f - aa;
        gr[r][i] = gr[r][i] * om + (1.f - cr * wsum) * aa;
        gg[r][i] = gg[r][i] * om + (1.f - cg * wsum) * aa;
        gb[r][i] = gb[r][i] * om + (1.f - cb * wsum) * aa;
      }
    }
  }

  *(float4*)(out + base)                 = make_float4(1.f - gr[0][0], 1.f - gr[0][1], 1.f - gr[0][2], 1.f - gr[0][3]);
  *(float4*)(out + base + IMW)           = make_float4(1.f - gr[1][0], 1.f - gr[1][1], 1.f - gr[1][2], 1.f - gr[1][3]);
  *(float4*)(out + base + plane)         = make_float4(1.f - gg[0][0], 1.f - gg[0][1], 1.f - gg[0][2], 1.f - gg[0][3]);
  *(float4*)(out + base + plane + IMW)   = make_float4(1.f - gg[1][0], 1.f - gg[1][1], 1.f - gg[1][2], 1.f - gg[1][3]);
  *(float4*)(out + base + 2 * plane)     = make_float4(1.f - gb[0][0], 1.f - gb[0][1], 1.f - gb[0][2], 1.f - gb[0][3]);
  *(float4*)(out + base + 2 * plane + IMW) = make_float4(1.f - gb[1][0], 1.f - gb[1][1], 1.f - gb[1][2], 1.f - gb[1][3]);
  *(float4*)(out + base + 3 * plane)     = a3;
  *(float4*)(out + base + 3 * plane + IMW) = b3;
}

extern "C" void kernel_launch(void* const* d_in, const int* in_sizes, int n_in,
                              void* d_out, int out_size, void* d_ws, size_t ws_size,
                              hipStream_t stream) {
  const float* images = (const float*)d_in[0];   // (B,4,H,W) f32
  const float* traj   = (const float*)d_in[1];   // (B,4,N)   f32
  const float* colors = (const float*)d_in[2];   // (B,4)     f32
  const float* brush  = (const float*)d_in[3];   // (4,HB,HB) f32
  float* outp = (float*)d_out;                   // (B,4,H,W) f32

  fused_paint_kernel<<<dim3(IMW / TPW, IMH / TPH, BATCH), 256, 0, stream>>>(
      images, traj, colors, brush, outp);
}

// Round 7
// 15.704 us; speedup vs baseline: 1.1938x; 1.1938x over previous
//
#include <hip/hip_runtime.h>
#include <math.h>

#define BATCH 4
#define NPTS  32
#define IMH   512
#define IMW   512
#define HB    64
#define TPW   128   // tile width  (32 lanes x 4 px)
#define TPH   8     // tile height (8 rows; wave w owns rows 2w, 2w+1)

// Single fused kernel, zero barriers, zero LDS, 4 px/thread (register-light).
// Cull uses only traj-direct data (x,y,z); waves with no surviving strokes skip
// the PCR spline AND the composite entirely (pure streaming copy early-exit).
// Surviving waves: PCR spline (5 steps, fast-rcp), ctz-ordered composite (exact order).
__global__ __launch_bounds__(256) void fused_paint_kernel(
    const float* __restrict__ images, const float* __restrict__ traj,
    const float* __restrict__ colors, const float* __restrict__ brush,
    float* __restrict__ out) {
  int b = blockIdx.z;
  int t = threadIdx.x;
  int lane = t & 63;
  int w = t >> 6;
  int tx = t & 31, ty = t >> 5;
  int c0 = blockIdx.x * TPW, r0 = blockIdx.y * TPH;
  int col = c0 + tx * 4, row = r0 + ty;
  size_t plane = (size_t)IMH * IMW;
  size_t base = (size_t)b * 4 * plane + (size_t)row * IMW + col;

  // Streaming loads first — HBM latency hides under the cull (and spline).
  float4 v0 = *(const float4*)(images + base);
  float4 v1 = *(const float4*)(images + base + plane);
  float4 v2 = *(const float4*)(images + base + 2 * plane);
  float4 v3 = *(const float4*)(images + base + 3 * plane);

  // ---- cull from traj-direct data (no spline needed) ----
  const float* tb = traj + b * 4 * NPTS;
  float tsv = 0.f, xv = 0.f, yv = 0.f, zv = 0.f;
  if (lane < NPTS) {
    tsv = tb[0 * NPTS + lane];
    xv  = tb[1 * NPTS + lane];
    yv  = tb[2 * NPTS + lane];
    zv  = tb[3 * NPTS + lane];
  }
  float scale = fminf(fmaxf(zv, 0.001f), 1.0f);
  float iscv  = 1.0f / scale;
  // Exact support radius: 33.42*scale (alpha>0 disc 32 + bilinear sqrt(2)).
  float R = scale * 33.6f + 0.5f;
  float sx0 = (float)c0, sx1 = (float)(c0 + TPW - 1);
  float sy0 = (float)(r0 + w * 2), sy1 = sy0 + 1.f;
  bool pred = (lane < NPTS) && (zv > 0.f) &&
              (xv + R >= sx0) && (xv - R <= sx1) &&
              (yv + R >= sy0) && (yv - R <= sy1);
  unsigned long long mask = __ballot(pred);

  if (mask == 0ull) {   // wave-uniform: pure streaming copy, no spline, no composite
    *(float4*)(out + base)             = v0;
    *(float4*)(out + base + plane)     = v1;
    *(float4*)(out + base + 2 * plane) = v2;
    *(float4*)(out + base + 3 * plane) = v3;
    return;
  }

  // ---- per-wave spline via PCR (lane k = node k), fast-rcp chains ----
  float ts1 = __shfl_down(tsv, 1);
  float x1  = __shfl_down(xv, 1);
  float y1  = __shfl_down(yv, 1);
  float hv  = ts1 - tsv;
  float rhv = __builtin_amdgcn_rcpf(hv);
  float sxv = (x1 - xv) * rhv;
  float syv = (y1 - yv) * rhv;
  float am  = __shfl_up(hv, 1);
  float smx = __shfl_up(sxv, 1);
  float smy = __shfl_up(syv, 1);
  bool interior = (lane >= 1) && (lane <= NPTS - 2);
  float A_ = interior ? am : 0.f;
  float C_ = interior ? hv : 0.f;
  float B_ = interior ? 2.0f * (am + hv) : 1.f;
  float Rx = interior ? 6.0f * (sxv - smx) : 0.f;
  float Ry = interior ? 6.0f * (syv - smy) : 0.f;

  #pragma unroll
  for (int d = 1; d < NPTS; d <<= 1) {
    int lo = lane - d; lo = lo < 0 ? 0 : lo;
    int hi = lane + d; hi = hi > NPTS - 1 ? NPTS - 1 : hi;
    float a_lo = __shfl(A_, lo), b_lo = __shfl(B_, lo), c_lo = __shfl(C_, lo);
    float rx_lo = __shfl(Rx, lo), ry_lo = __shfl(Ry, lo);
    float a_hi = __shfl(A_, hi), b_hi = __shfl(B_, hi), c_hi = __shfl(C_, hi);
    float rx_hi = __shfl(Rx, hi), ry_hi = __shfl(Ry, hi);
    float alpha = A_ * __builtin_amdgcn_rcpf(b_lo);
    float gamma = C_ * __builtin_amdgcn_rcpf(b_hi);
    B_ = B_ - alpha * c_lo - gamma * a_hi;
    Rx = Rx - alpha * rx_lo - gamma * rx_hi;
    Ry = Ry - alpha * ry_lo - gamma * ry_hi;
    A_ = -alpha * a_lo;
    C_ = -gamma * c_hi;
  }
  float rB  = __builtin_amdgcn_rcpf(B_);
  float Mxv = Rx * rB;   // M[0]=M[31]=0 via identity rows
  float Myv = Ry * rB;

  float Mx1  = __shfl_down(Mxv, 1);
  float My1  = __shfl_down(Myv, 1);
  float sx30 = __shfl(sxv, NPTS - 2);
  float sy30 = __shfl(syv, NPTS - 2);
  float h30  = __shfl(hv,  NPTS - 2);
  float Mx30 = __shfl(Mxv, NPTS - 2);
  float My30 = __shfl(Myv, NPTS - 2);
  float Mx31 = __shfl(Mxv, NPTS - 1);
  float My31 = __shfl(Myv, NPTS - 1);

  float dX, dY;
  if (lane < NPTS - 1) {
    dX = sxv - hv * (2.0f * Mxv + Mx1) * (1.0f / 6.0f);
    dY = syv - hv * (2.0f * Myv + My1) * (1.0f / 6.0f);
  } else {
    dX = sx30 + h30 * (2.0f * Mx31 + Mx30) * (1.0f / 6.0f);
    dY = sy30 + h30 * (2.0f * My31 + My30) * (1.0f / 6.0f);
  }
  float cthv = 1.f, sthv = 0.f;
  {
    float r2 = dX * dX + dY * dY;
    if (r2 > 0.f) { float inv = 1.0f / sqrtf(r2); cthv = dX * inv; sthv = -dY * inv; }
  }

  float cr = colors[b * 4 + 0], cg = colors[b * 4 + 1];
  float cb = colors[b * 4 + 2], ca = colors[b * 4 + 3];

  float gr[4], gg[4], gb[4];
  gr[0] = 1.f - v0.x; gr[1] = 1.f - v0.y; gr[2] = 1.f - v0.z; gr[3] = 1.f - v0.w;
  gg[0] = 1.f - v1.x; gg[1] = 1.f - v1.y; gg[2] = 1.f - v1.z; gg[3] = 1.f - v1.w;
  gb[0] = 1.f - v2.x; gb[1] = 1.f - v2.y; gb[2] = 1.f - v2.z; gb[3] = 1.f - v2.w;

  const float* bA = brush + 3 * HB * HB;   // alpha plane, 16KB -> L1-resident
  float fry = (float)row;

  // Surviving strokes in ascending k (compositing order exact).
  while (mask) {
    int src = __builtin_ctzll(mask);
    mask &= mask - 1;
    float spx = __shfl(xv, src), spy = __shfl(yv, src);
    float cth = __shfl(cthv, src), sth = __shfl(sthv, src), isc = __shfl(iscv, src);
    float dy = fry - spy;
    float dx0 = (float)col - spx;
    float lxb = (cth * dx0 - sth * dy) * isc + 0.5f * (HB - 1);
    float lyb = (sth * dx0 + cth * dy) * isc + 0.5f * (HB - 1);
    float cdx = cth * isc, sdx = sth * isc;
    #pragma unroll
    for (int i = 0; i < 4; ++i) {
      float lx = lxb + cdx * (float)i;
      float ly = lyb + sdx * (float)i;
      if (lx <= -1.f || lx >= (float)HB || ly <= -1.f || ly >= (float)HB) continue;
      float x0f = floorf(lx), y0f = floorf(ly);
      float wx = lx - x0f, wy = ly - y0f;
      int x0 = (int)x0f, y0 = (int)y0f;
      int x1i = x0 + 1, y1i = y0 + 1;
      bool xv0 = (x0  >= 0) && (x0  < HB);
      bool xv1 = (x1i >= 0) && (x1i < HB);
      bool yv0 = (y0  >= 0) && (y0  < HB);
      bool yv1 = (y1i >= 0) && (y1i < HB);
      int xc0 = min(max(x0,  0), HB - 1);
      int xc1 = min(max(x1i, 0), HB - 1);
      int yc0 = min(max(y0,  0), HB - 1);
      int yc1 = min(max(y1i, 0), HB - 1);
      float f00 = (xv0 && yv0) ? 1.f : 0.f;
      float f01 = (xv1 && yv0) ? 1.f : 0.f;
      float f10 = (xv0 && yv1) ? 1.f : 0.f;
      float f11 = (xv1 && yv1) ? 1.f : 0.f;
      float v00 = bA[yc0 * HB + xc0] * f00;
      float v01 = bA[yc0 * HB + xc1] * f01;
      float v10 = bA[yc1 * HB + xc0] * f10;
      float v11 = bA[yc1 * HB + xc1] * f11;
      float w00 = (1.f - wx) * (1.f - wy);
      float w01 = wx * (1.f - wy);
      float w10 = (1.f - wx) * wy;
      float w11 = wx * wy;
      float asamp = v00 * w00 + v01 * w01 + v10 * w10 + v11 * w11;
      float aa    = ca * asamp;                                      // sprite alpha
      float wsum  = f00 * w00 + f01 * w01 + f10 * w10 + f11 * w11;   // rgb coverage
      float om = 1.f - aa;
      gr[i] = gr[i] * om + (1.f - cr * wsum) * aa;
      gg[i] = gg[i] * om + (1.f - cg * wsum) * aa;
      gb[i] = gb[i] * om + (1.f - cb * wsum) * aa;
    }
  }

  *(float4*)(out + base)             = make_float4(1.f - gr[0], 1.f - gr[1], 1.f - gr[2], 1.f - gr[3]);
  *(float4*)(out + base + plane)     = make_float4(1.f - gg[0], 1.f - gg[1], 1.f - gg[2], 1.f - gg[3]);
  *(float4*)(out + base + 2 * plane) = make_float4(1.f - gb[0], 1.f - gb[1], 1.f - gb[2], 1.f - gb[3]);
  *(float4*)(out + base + 3 * plane) = v3;
}

extern "C" void kernel_launch(void* const* d_in, const int* in_sizes, int n_in,
                              void* d_out, int out_size, void* d_ws, size_t ws_size,
                              hipStream_t stream) {
  const float* images = (const float*)d_in[0];   // (B,4,H,W) f32
  const float* traj   = (const float*)d_in[1];   // (B,4,N)   f32
  const float* colors = (const float*)d_in[2];   // (B,4)     f32
  const float* brush  = (const float*)d_in[3];   // (4,HB,HB) f32
  float* outp = (float*)d_out;                   // (B,4,H,W) f32

  fused_paint_kernel<<<dim3(IMW / TPW, IMH / TPH, BATCH), 256, 0, stream>>>(
      images, traj, colors, brush, outp);
}